// Round 8
// baseline (11364.561 us; speedup 1.0000x reference)
//
#include <hip/hip_runtime.h>

// DescentPredictor: 50 SGD steps on y for E(x,y)=MLP([x;y]).
// R8: zero-barrier wave-autonomous design (R7) restructured to avoid the clang
// ICE: plain float arrays at function boundaries, no nullable vector-array
// pointers. Each wave owns 16 rows end-to-end; weights are the MFMA A-operand,
// data rows the B-operand; all row stats via 2 shfl_xor; C->B-frag transform is
// an in-register 4x4 dword transpose. No __syncthreads in the 50-iter loop.

typedef unsigned short u16;
typedef u16 u16x8 __attribute__((ext_vector_type(8)));
typedef float f32x4 __attribute__((ext_vector_type(4)));
typedef int i32x4 __attribute__((ext_vector_type(4)));
typedef __bf16 bf16x8 __attribute__((ext_vector_type(8)));

#define ITERS 50
#define EPSF 1e-5f
static constexpr float SCALE = 0.1f / 16384.0f;  // LR / B

// per-copy weight span (bytes) and offsets within a copy
#define CSPAN     557056
#define OFF_W0X   0         // bf16 [256][512]
#define OFF_W0Y   262144    // i8 [256][64]
#define OFF_W0YT  278528    // i8 [64][256]
#define OFF_W1    294912    // i8 [256][256]
#define OFF_W1T   360448
#define OFF_W2    425984
#define OFF_W2T   491520
#define NCOPY     8
#define OFF_WSC   (NCOPY * CSPAN)   // f32[8]: raw absmax of {W0y, W1, W2}

__device__ __forceinline__ u16 f2bf(float f) {  // RNE
  unsigned int u = __builtin_bit_cast(unsigned int, f);
  return (u16)((u + 0x7FFFu + ((u >> 16) & 1u)) >> 16);
}
__device__ __forceinline__ float uplo(int p) {
  return __builtin_bit_cast(float, (unsigned int)p << 16);
}
__device__ __forceinline__ float uphi(int p) {
  return __builtin_bit_cast(float, (unsigned int)p & 0xffff0000u);
}
__device__ __forceinline__ int packbf2(float lo, float hi) {  // trunc pair->dword
  return __builtin_amdgcn_perm(__builtin_bit_cast(int, hi),
                               __builtin_bit_cast(int, lo), 0x07060302);
}
__device__ __forceinline__ int pack_i8x4(float a0, float a1, float a2, float a3,
                                         float qs) {
  int b0 = __float2int_rn(a0 * qs), b1 = __float2int_rn(a1 * qs);
  int b2 = __float2int_rn(a2 * qs), b3 = __float2int_rn(a3 * qs);
  int t01 = __builtin_amdgcn_perm(b1, b0, 0x00000400);
  int t23 = __builtin_amdgcn_perm(b3, b2, 0x00000400);
  return __builtin_amdgcn_perm(t23, t01, 0x05040100);
}
__device__ __forceinline__ f32x4 mfma16(u16x8 a, u16x8 b, f32x4 c) {
  return __builtin_amdgcn_mfma_f32_16x16x32_bf16(
      __builtin_bit_cast(bf16x8, a), __builtin_bit_cast(bf16x8, b), c, 0, 0, 0);
}
__device__ __forceinline__ i32x4 mfma8(i32x4 a, i32x4 b, i32x4 c) {
  return __builtin_amdgcn_mfma_i32_16x16x64_i8(a, b, c, 0, 0, 0);
}
__device__ __forceinline__ float rowsum(float v) {
  v += __shfl_xor(v, 16); return v + __shfl_xor(v, 32);
}
__device__ __forceinline__ float rowmax(float v) {
  v = fmaxf(v, __shfl_xor(v, 16)); return fmaxf(v, __shfl_xor(v, 32));
}

// 4x4 dword transpose among lanes {l, l^16, l^32, l^48}: out[d] = lane d's a[q].
__device__ __forceinline__ void xpose4(int a0, int a1, int a2, int a3,
                                       i32x4& out, int q) {
  int pa0 = __shfl_xor(a0, 16), pa1 = __shfl_xor(a1, 16);
  int pa2 = __shfl_xor(a2, 16), pa3 = __shfl_xor(a3, 16);
  int c0 = (q & 1) ? pa1 : a0, c1 = (q & 1) ? a1 : pa0;
  int c2 = (q & 1) ? pa3 : a2, c3 = (q & 1) ? a3 : pa2;
  int pc0 = __shfl_xor(c0, 32), pc1 = __shfl_xor(c1, 32);
  int pc2 = __shfl_xor(c2, 32), pc3 = __shfl_xor(c3, 32);
  out[0] = (q & 2) ? pc2 : c0; out[1] = (q & 2) ? pc3 : c1;
  out[2] = (q & 2) ? c2 : pc0; out[3] = (q & 2) ? c3 : pc1;
}

// ---------------- prep kernels (write NCOPY copies) --------------------------
__global__ void prep_w0x(const float* __restrict__ W0, char* __restrict__ ws) {
  int i = blockIdx.x * 256 + threadIdx.x;
  u16* dst = (u16*)(ws + (size_t)blockIdx.y * CSPAN + OFF_W0X);
  if (i < 131072) dst[i] = f2bf(W0[(i >> 9) * 576 + (i & 511)]);
}

__global__ void prep_init(float* sc) { if (threadIdx.x < 8) sc[threadIdx.x] = 0.f; }

__global__ void prep_absmax(const float* __restrict__ W0, const float* __restrict__ W1,
                            const float* __restrict__ W2, float* sc) {
  int i = blockIdx.x * 256 + threadIdx.x;
  float v; int slot;
  if (i < 16384)       { v = fabsf(W0[(i >> 6) * 576 + 512 + (i & 63)]); slot = 0; }
  else if (i < 81920)  { v = fabsf(W1[i - 16384]); slot = 1; }
  else                 { v = fabsf(W2[i - 81920]); slot = 2; }
#pragma unroll
  for (int m = 1; m < 64; m <<= 1) v = fmaxf(v, __shfl_xor(v, m));
  if ((threadIdx.x & 63) == 0)
    atomicMax((unsigned int*)(sc + slot), __builtin_bit_cast(unsigned int, v));
}

__global__ void prep_quant(const float* __restrict__ W0, const float* __restrict__ W1,
                           const float* __restrict__ W2, char* __restrict__ ws) {
  const float* sc = (const float*)(ws + OFF_WSC);
  char* wsb = ws + (size_t)blockIdx.y * CSPAN;
  int wid = blockIdx.x * 4 + (threadIdx.x >> 6);
  int lane = threadIdx.x & 63;
  if (wid < 256) {
    float qs = sc[0] > 0.f ? 127.f / sc[0] : 0.f;
    float v = W0[wid * 576 + 512 + lane];
    wsb[OFF_W0Y + wid * 64 + lane] = (char)__float2int_rn(v * qs);
    return;
  }
  float v[4]; char* dst; float qs;
  if (wid < 320) {
    int r = wid - 256; qs = sc[0] > 0.f ? 127.f / sc[0] : 0.f;
#pragma unroll
    for (int e = 0; e < 4; ++e) v[e] = W0[(4 * lane + e) * 576 + 512 + r];
    dst = wsb + OFF_W0YT + r * 256;
  } else if (wid < 576) {
    int r = wid - 320; qs = sc[1] > 0.f ? 127.f / sc[1] : 0.f;
#pragma unroll
    for (int e = 0; e < 4; ++e) v[e] = W1[r * 256 + 4 * lane + e];
    dst = wsb + OFF_W1 + r * 256;
  } else if (wid < 832) {
    int r = wid - 576; qs = sc[1] > 0.f ? 127.f / sc[1] : 0.f;
#pragma unroll
    for (int e = 0; e < 4; ++e) v[e] = W1[(4 * lane + e) * 256 + r];
    dst = wsb + OFF_W1T + r * 256;
  } else if (wid < 1088) {
    int r = wid - 832; qs = sc[2] > 0.f ? 127.f / sc[2] : 0.f;
#pragma unroll
    for (int e = 0; e < 4; ++e) v[e] = W2[r * 256 + 4 * lane + e];
    dst = wsb + OFF_W2 + r * 256;
  } else {
    int r = wid - 1088; qs = sc[2] > 0.f ? 127.f / sc[2] : 0.f;
#pragma unroll
    for (int e = 0; e < 4; ++e) v[e] = W2[(4 * lane + e) * 256 + r];
    dst = wsb + OFF_W2T + r * 256;
  }
  ((int*)dst)[lane] = pack_i8x4(v[0], v[1], v[2], v[3], qs);
}

// ---------------- per-wave GEMM: 16 Ntiles x K=256, B frags in regs ----------
__device__ __forceinline__ void gemmW(const char* __restrict__ W,
                                      const i32x4 (&B)[4], i32x4 (&acc)[16],
                                      int l15, int q) {
  const i32x4 zero4 = {0, 0, 0, 0};
  const char* base = W + l15 * 256 + 16 * q;
#pragma unroll
  for (int tt = 0; tt < 16; ++tt) acc[tt] = zero4;
#pragma unroll
  for (int ks = 0; ks < 4; ++ks)
#pragma unroll
    for (int tt = 0; tt < 16; ++tt) {
      i32x4 wf = *(const i32x4*)(base + tt * 4096 + ks * 64);
      acc[tt] = mfma8(wf, B[ks], acc[tt]);
    }
}

// ---------------- EW passes: z prefilled by caller; row stats via shfl -------
__device__ __forceinline__ void ln_fwd(float (&z)[16][4], const float* g,
                                       const float* be, int (&zh)[32],
                                       float& inv_out, float& sG,
                                       i32x4 (&fr)[4], int q) {
  float s = 0.f, ss = 0.f;
#pragma unroll
  for (int tt = 0; tt < 16; ++tt)
#pragma unroll
    for (int rr = 0; rr < 4; ++rr) { float v = z[tt][rr]; s += v; ss += v * v; }
  s = rowsum(s); ss = rowsum(ss);
  const float mu = s * (1.f / 256.f);
  const float inv = rsqrtf(ss * (1.f / 256.f) - mu * mu + EPSF);
  inv_out = inv;
  float ma = 0.f;
#pragma unroll
  for (int tt = 0; tt < 16; ++tt) {
    f32x4 gv = *(const f32x4*)(g + 16 * tt + 4 * q);
    f32x4 bev = *(const f32x4*)(be + 16 * tt + 4 * q);
    float zn0 = (z[tt][0] - mu) * inv, zn1 = (z[tt][1] - mu) * inv;
    float zn2 = (z[tt][2] - mu) * inv, zn3 = (z[tt][3] - mu) * inv;
    zh[2 * tt] = packbf2(zn0, zn1);
    zh[2 * tt + 1] = packbf2(zn2, zn3);
    float zn[4] = {zn0, zn1, zn2, zn3};
#pragma unroll
    for (int rr = 0; rr < 4; ++rr) {
      float u = zn[rr] * gv[rr] + bev[rr];
      float a = u * __builtin_amdgcn_rcpf(1.f + __expf(-u));  // SiLU
      z[tt][rr] = a;
      ma = fmaxf(ma, fabsf(a));
    }
  }
  ma = rowmax(ma);
  float qa = ma > 0.f ? 127.f / ma : 0.f;
  sG = ma * (1.f / 127.f);
  int dw[16];
#pragma unroll
  for (int tt = 0; tt < 16; ++tt)
    dw[tt] = pack_i8x4(z[tt][0], z[tt][1], z[tt][2], z[tt][3], qa);
#pragma unroll
  for (int ks = 0; ks < 4; ++ks)
    xpose4(dw[4 * ks], dw[4 * ks + 1], dw[4 * ks + 2], dw[4 * ks + 3], fr[ks], q);
}

__device__ __forceinline__ void ln_l2(float (&z)[16][4], const float* g,
                                      const float* be, const float* wo,
                                      float& sG, i32x4 (&fr)[4], int q) {
  float s = 0.f, ss = 0.f;
#pragma unroll
  for (int tt = 0; tt < 16; ++tt)
#pragma unroll
    for (int rr = 0; rr < 4; ++rr) { float v = z[tt][rr]; s += v; ss += v * v; }
  s = rowsum(s); ss = rowsum(ss);
  const float mu = s * (1.f / 256.f);
  const float inv = rsqrtf(ss * (1.f / 256.f) - mu * mu + EPSF);
  float s1 = 0.f, s2 = 0.f;
#pragma unroll
  for (int tt = 0; tt < 16; ++tt) {
    f32x4 gv = *(const f32x4*)(g + 16 * tt + 4 * q);
    f32x4 bev = *(const f32x4*)(be + 16 * tt + 4 * q);
    f32x4 wv = *(const f32x4*)(wo + 16 * tt + 4 * q);
#pragma unroll
    for (int rr = 0; rr < 4; ++rr) {
      float zn = (z[tt][rr] - mu) * inv;
      z[tt][rr] = zn;
      float u = zn * gv[rr] + bev[rr];
      float sg = __builtin_amdgcn_rcpf(1.f + __expf(-u));
      float du = wv[rr] * sg * (1.f + u * (1.f - sg));
      float d = du * gv[rr];
      s1 += d; s2 += d * zn;
    }
  }
  s1 = rowsum(s1); s2 = rowsum(s2);
  const float m1 = s1 * (1.f / 256.f), m2 = s2 * (1.f / 256.f);
  float mx = 0.f;
#pragma unroll
  for (int tt = 0; tt < 16; ++tt) {
    f32x4 gv = *(const f32x4*)(g + 16 * tt + 4 * q);
    f32x4 bev = *(const f32x4*)(be + 16 * tt + 4 * q);
    f32x4 wv = *(const f32x4*)(wo + 16 * tt + 4 * q);
#pragma unroll
    for (int rr = 0; rr < 4; ++rr) {
      float zn = z[tt][rr];
      float u = zn * gv[rr] + bev[rr];
      float sg = __builtin_amdgcn_rcpf(1.f + __expf(-u));
      float du = wv[rr] * sg * (1.f + u * (1.f - sg));
      float dz = inv * (du * gv[rr] - m1 - zn * m2);
      z[tt][rr] = dz;
      mx = fmaxf(mx, fabsf(dz));
    }
  }
  mx = rowmax(mx);
  float qd = mx > 0.f ? 127.f / mx : 0.f;
  sG = mx * (1.f / 127.f);
  int dw[16];
#pragma unroll
  for (int tt = 0; tt < 16; ++tt)
    dw[tt] = pack_i8x4(z[tt][0], z[tt][1], z[tt][2], z[tt][3], qd);
#pragma unroll
  for (int ks = 0; ks < 4; ++ks)
    xpose4(dw[4 * ks], dw[4 * ks + 1], dw[4 * ks + 2], dw[4 * ks + 3], fr[ks], q);
}

__device__ __forceinline__ void ln_bwd(float (&da)[16][4], const int (&zh)[32],
                                       float inv, const float* g, const float* be,
                                       float& sG, i32x4 (&fr)[4], int q) {
  float s1 = 0.f, s2 = 0.f;
#pragma unroll
  for (int tt = 0; tt < 16; ++tt) {
    f32x4 gv = *(const f32x4*)(g + 16 * tt + 4 * q);
    f32x4 bev = *(const f32x4*)(be + 16 * tt + 4 * q);
    float zn[4] = {uplo(zh[2 * tt]), uphi(zh[2 * tt]),
                   uplo(zh[2 * tt + 1]), uphi(zh[2 * tt + 1])};
#pragma unroll
    for (int rr = 0; rr < 4; ++rr) {
      float u = zn[rr] * gv[rr] + bev[rr];
      float sg = __builtin_amdgcn_rcpf(1.f + __expf(-u));
      float du = da[tt][rr] * sg * (1.f + u * (1.f - sg));
      float d = du * gv[rr];
      da[tt][rr] = d; s1 += d; s2 += d * zn[rr];
    }
  }
  s1 = rowsum(s1); s2 = rowsum(s2);
  const float m1 = s1 * (1.f / 256.f), m2 = s2 * (1.f / 256.f);
  float mx = 0.f;
#pragma unroll
  for (int tt = 0; tt < 16; ++tt) {
    float zn[4] = {uplo(zh[2 * tt]), uphi(zh[2 * tt]),
                   uplo(zh[2 * tt + 1]), uphi(zh[2 * tt + 1])};
#pragma unroll
    for (int rr = 0; rr < 4; ++rr) {
      float dz = inv * (da[tt][rr] - m1 - zn[rr] * m2);
      da[tt][rr] = dz;
      mx = fmaxf(mx, fabsf(dz));
    }
  }
  mx = rowmax(mx);
  float qd = mx > 0.f ? 127.f / mx : 0.f;
  sG = mx * (1.f / 127.f);
  int dw[16];
#pragma unroll
  for (int tt = 0; tt < 16; ++tt)
    dw[tt] = pack_i8x4(da[tt][0], da[tt][1], da[tt][2], da[tt][3], qd);
#pragma unroll
  for (int ks = 0; ks < 4; ++ks)
    xpose4(dw[4 * ks], dw[4 * ks + 1], dw[4 * ks + 2], dw[4 * ks + 3], fr[ks], q);
}

// ---------------- main persistent kernel (no loop barriers) ------------------
__global__ __launch_bounds__(256, 1) void descent_kernel(
    const float* __restrict__ x, const float* __restrict__ y0,
    const float* __restrict__ b0, const float* __restrict__ g0, const float* __restrict__ be0,
    const float* __restrict__ b1, const float* __restrict__ g1, const float* __restrict__ be1,
    const float* __restrict__ b2, const float* __restrict__ g2, const float* __restrict__ be2,
    const float* __restrict__ wout, const char* __restrict__ ws, float* __restrict__ out) {
  __shared__ __align__(16) float params[9 * 256];  // g0 be0 g1 be1 g2 be2 b1 b2 wout

  const int t = threadIdx.x;
  const int w = t >> 6, lane = t & 63, l15 = lane & 15, q = lane >> 4;
  const int job = blockIdx.x * 4 + w;      // 1024 wave-jobs, 16 rows each
  const int drow = job * 16 + l15;         // this lane's data row

  const char* wsb = ws + (size_t)(blockIdx.x & (NCOPY - 1)) * CSPAN;
  const u16* W0X = (const u16*)(wsb + OFF_W0X);
  const char* W0Yq = wsb + OFF_W0Y;
  const char* W0YTq = wsb + OFF_W0YT;
  const char* W1q = wsb + OFF_W1;
  const char* W1Tq = wsb + OFF_W1T;
  const char* W2q = wsb + OFF_W2;
  const char* W2Tq = wsb + OFF_W2T;
  const float* scg = (const float*)(ws + OFF_WSC);
  const float sW0Yd = scg[0] * (1.f / 127.f);
  const float sW1d = scg[1] * (1.f / 127.f);
  const float sW2d = scg[2] * (1.f / 127.f);

  params[0 * 256 + t] = g0[t];  params[1 * 256 + t] = be0[t];
  params[2 * 256 + t] = g1[t];  params[3 * 256 + t] = be1[t];
  params[4 * 256 + t] = g2[t];  params[5 * 256 + t] = be2[t];
  params[6 * 256 + t] = b1[t];  params[7 * 256 + t] = b2[t];
  params[8 * 256 + t] = wout[t];

  // y master: yv[t4][rr] = y[drow][16*t4 + 4*q + rr]
  float yv[4][4];
#pragma unroll
  for (int t4 = 0; t4 < 4; ++t4) {
    f32x4 v = *(const f32x4*)(y0 + (size_t)drow * 64 + 16 * t4 + 4 * q);
    yv[t4][0] = v[0]; yv[t4][1] = v[1]; yv[t4][2] = v[2]; yv[t4][3] = v[3];
  }

  // Phase A: c = x @ W0x^T + b0, cRp[tt] = packed bf16 of c[drow][16tt+4q+..]
  int cRp[16][2];
  {
    f32x4 cA[16];
#pragma unroll
    for (int tt = 0; tt < 16; ++tt)
      cA[tt] = *(const f32x4*)(b0 + 16 * tt + 4 * q);
    const float* xr = x + (size_t)drow * 512;
    for (int kc = 0; kc < 16; ++kc) {
      f32x4 x0 = *(const f32x4*)(xr + kc * 32 + 8 * q);
      f32x4 x1 = *(const f32x4*)(xr + kc * 32 + 8 * q + 4);
      u16x8 xb;
#pragma unroll
      for (int e = 0; e < 4; ++e) { xb[e] = f2bf(x0[e]); xb[4 + e] = f2bf(x1[e]); }
#pragma unroll
      for (int tt = 0; tt < 16; ++tt) {
        u16x8 wf = *(const u16x8*)(W0X + (16 * tt + l15) * 512 + kc * 32 + 8 * q);
        cA[tt] = mfma16(wf, xb, cA[tt]);
      }
    }
#pragma unroll
    for (int tt = 0; tt < 16; ++tt) {
      cRp[tt][0] = packbf2(cA[tt][0], cA[tt][1]);
      cRp[tt][1] = packbf2(cA[tt][2], cA[tt][3]);
    }
  }
  __syncthreads();  // params ready (the ONLY barrier)

  int zh0[32], zh1[32];
  float inv0 = 0.f, inv1 = 0.f, sG = 0.f;
  i32x4 fr[4];
  float z[16][4];
  i32x4 acc[16];
  const i32x4 zero4 = {0, 0, 0, 0};

  for (int it = 0; it < ITERS; ++it) {
    // ---- y quant (row scale via 2 shfl) ----
    float my = 0.f;
#pragma unroll
    for (int t4 = 0; t4 < 4; ++t4)
#pragma unroll
      for (int rr = 0; rr < 4; ++rr) my = fmaxf(my, fabsf(yv[t4][rr]));
    my = rowmax(my);
    float qy = my > 0.f ? 127.f / my : 0.f;
    float sY = my * (1.f / 127.f);
    int yd0 = pack_i8x4(yv[0][0], yv[0][1], yv[0][2], yv[0][3], qy);
    int yd1 = pack_i8x4(yv[1][0], yv[1][1], yv[1][2], yv[1][3], qy);
    int yd2 = pack_i8x4(yv[2][0], yv[2][1], yv[2][2], yv[2][3], qy);
    int yd3 = pack_i8x4(yv[3][0], yv[3][1], yv[3][2], yv[3][3], qy);
    i32x4 yB;
    xpose4(yd0, yd1, yd2, yd3, yB, q);

    // ---- fwd0: z0 = cR + y @ W0y^T (K=64) ----
#pragma unroll
    for (int tt = 0; tt < 16; ++tt) {
      i32x4 wf = *(const i32x4*)(W0Yq + (16 * tt + l15) * 64 + 16 * q);
      acc[tt] = mfma8(wf, yB, zero4);
    }
    {
      float vs = sY * sW0Yd;
#pragma unroll
      for (int tt = 0; tt < 16; ++tt) {
        z[tt][0] = (float)acc[tt][0] * vs + uplo(cRp[tt][0]);
        z[tt][1] = (float)acc[tt][1] * vs + uphi(cRp[tt][0]);
        z[tt][2] = (float)acc[tt][2] * vs + uplo(cRp[tt][1]);
        z[tt][3] = (float)acc[tt][3] * vs + uphi(cRp[tt][1]);
      }
    }
    ln_fwd(z, &params[0 * 256], &params[1 * 256], zh0, inv0, sG, fr, q);

    // ---- fwd1 ----
    gemmW(W1q, fr, acc, l15, q);
    {
      float vs = sG * sW1d;
#pragma unroll
      for (int tt = 0; tt < 16; ++tt) {
        f32x4 bv = *(const f32x4*)(&params[6 * 256] + 16 * tt + 4 * q);
#pragma unroll
        for (int rr = 0; rr < 4; ++rr)
          z[tt][rr] = (float)acc[tt][rr] * vs + bv[rr];
      }
    }
    ln_fwd(z, &params[2 * 256], &params[3 * 256], zh1, inv1, sG, fr, q);

    // ---- fwd2 + top-grad + LN-bwd (fused) ----
    gemmW(W2q, fr, acc, l15, q);
    {
      float vs = sG * sW2d;
#pragma unroll
      for (int tt = 0; tt < 16; ++tt) {
        f32x4 bv = *(const f32x4*)(&params[7 * 256] + 16 * tt + 4 * q);
#pragma unroll
        for (int rr = 0; rr < 4; ++rr)
          z[tt][rr] = (float)acc[tt][rr] * vs + bv[rr];
      }
    }
    ln_l2(z, &params[4 * 256], &params[5 * 256], &params[8 * 256], sG, fr, q);

    // ---- bwd2: da1 = dz2 @ W2 ----
    gemmW(W2Tq, fr, acc, l15, q);
    {
      float vs = sG * sW2d;
#pragma unroll
      for (int tt = 0; tt < 16; ++tt)
#pragma unroll
        for (int rr = 0; rr < 4; ++rr) z[tt][rr] = (float)acc[tt][rr] * vs;
    }
    ln_bwd(z, zh1, inv1, &params[2 * 256], &params[3 * 256], sG, fr, q);

    // ---- bwd1: da0 = dz1 @ W1 ----
    gemmW(W1Tq, fr, acc, l15, q);
    {
      float vs = sG * sW1d;
#pragma unroll
      for (int tt = 0; tt < 16; ++tt)
#pragma unroll
        for (int rr = 0; rr < 4; ++rr) z[tt][rr] = (float)acc[tt][rr] * vs;
    }
    ln_bwd(z, zh0, inv0, &params[0 * 256], &params[1 * 256], sG, fr, q);

    // ---- dy = dz0 @ W0y ; y -= (LR/B)*dy ----
    const float dsc = sG * sW0Yd * SCALE;
#pragma unroll
    for (int t4 = 0; t4 < 4; ++t4) {
      i32x4 dy = zero4;
#pragma unroll
      for (int ks = 0; ks < 4; ++ks) {
        i32x4 wf = *(const i32x4*)(W0YTq + (16 * t4 + l15) * 256 + ks * 64 + 16 * q);
        dy = mfma8(wf, fr[ks], dy);
      }
#pragma unroll
      for (int rr = 0; rr < 4; ++rr) yv[t4][rr] -= (float)dy[rr] * dsc;
    }
  }

#pragma unroll
  for (int t4 = 0; t4 < 4; ++t4) {
    f32x4 o;
    o[0] = yv[t4][0]; o[1] = yv[t4][1]; o[2] = yv[t4][2]; o[3] = yv[t4][3];
    *(f32x4*)(out + (size_t)drow * 64 + 16 * t4 + 4 * q) = o;
  }
}

extern "C" void kernel_launch(void* const* d_in, const int* in_sizes, int n_in,
                              void* d_out, int out_size, void* d_ws, size_t ws_size,
                              hipStream_t stream) {
  const float* x   = (const float*)d_in[0];
  const float* y0  = (const float*)d_in[1];
  const float* W0  = (const float*)d_in[2];
  const float* b0  = (const float*)d_in[3];
  const float* g0  = (const float*)d_in[4];
  const float* be0 = (const float*)d_in[5];
  const float* W1  = (const float*)d_in[6];
  const float* b1  = (const float*)d_in[7];
  const float* g1  = (const float*)d_in[8];
  const float* be1 = (const float*)d_in[9];
  const float* W2  = (const float*)d_in[10];
  const float* b2  = (const float*)d_in[11];
  const float* g2  = (const float*)d_in[12];
  const float* be2 = (const float*)d_in[13];
  const float* wout = (const float*)d_in[14];
  char* ws = (char*)d_ws;  // needs NCOPY*CSPAN + 32 = 4,456,480 B
  float* out = (float*)d_out;

  prep_init<<<1, 64, 0, stream>>>((float*)(ws + OFF_WSC));
  prep_absmax<<<576, 256, 0, stream>>>(W0, W1, W2, (float*)(ws + OFF_WSC));
  prep_w0x<<<dim3(512, NCOPY), 256, 0, stream>>>(W0, ws);
  prep_quant<<<dim3(336, NCOPY), 256, 0, stream>>>(W0, W1, W2, ws);
  descent_kernel<<<256, 256, 0, stream>>>(x, y0, b0, g0, be0, b1, g1, be1,
                                          b2, g2, be2, wout, ws, out);
}